// Round 12
// baseline (176.678 us; speedup 1.0000x reference)
//
#include <hip/hip_runtime.h>

typedef __attribute__((ext_vector_type(8))) short short8;
typedef __attribute__((ext_vector_type(4))) float floatx4;
typedef __attribute__((ext_vector_type(16))) float floatx16;
typedef __attribute__((ext_vector_type(4))) unsigned short ushort4v;

__device__ __forceinline__ unsigned short f2bf(float f) {
  unsigned int u = __float_as_uint(f);
  u += 0x7FFFu + ((u >> 16) & 1u);           // round-to-nearest-even
  return (unsigned short)(u >> 16);
}

__device__ __forceinline__ unsigned int cvt_pk_bf16(float lo, float hi) {
  unsigned int r;
  asm("v_cvt_pk_bf16_f32 %0, %1, %2" : "=v"(r) : "v"(lo), "v"(hi));
  return r;
}

__device__ __forceinline__ void async_copy16(const void* g, void* l) {
  __builtin_amdgcn_global_load_lds(
      (const __attribute__((address_space(1))) unsigned int*)g,
      (__attribute__((address_space(3))) unsigned int*)l, 16, 0, 0);
}

__device__ __forceinline__ float fexp2(float x) {
#if __has_builtin(__builtin_amdgcn_exp2f)
  return __builtin_amdgcn_exp2f(x);
#else
  return exp2f(x);
#endif
}

// ---------------------------------------------------------------- convert (fused)
__global__ __launch_bounds__(256) void cvt_all(const float* __restrict__ x,
                                               const float* __restrict__ wq,
                                               const float* __restrict__ wo,
                                               unsigned short* __restrict__ Xb,
                                               unsigned short* __restrict__ Wqb,
                                               unsigned short* __restrict__ Wob) {
  int i = blockIdx.x * blockDim.x + threadIdx.x;
  const float* src;
  unsigned short* dst;
  int off;
  if (i < 2097152) { src = x;  dst = Xb;  off = i; }
  else if (i < 2883584) { src = wq; dst = Wqb; off = i - 2097152; }
  else { src = wo; dst = Wob; off = i - 2883584; }
  float4 v = reinterpret_cast<const float4*>(src)[off];
  ushort4v o;
  o[0] = f2bf(v.x); o[1] = f2bf(v.y); o[2] = f2bf(v.z); o[3] = f2bf(v.w);
  reinterpret_cast<ushort4v*>(dst)[off] = o;
}

// ---------------------------------------------------------------- GEMM NT 128x128 (R11)
template <int MODE, int NX>
__global__ __launch_bounds__(256, 4) void gemm_nt(const unsigned short* __restrict__ A,
                                                  const unsigned short* __restrict__ B,
                                                  const float* __restrict__ bias,
                                                  void* __restrict__ C,
                                                  int M, int N, int K) {
  __shared__ __align__(16) unsigned short lds[2][128 * 64];
  unsigned short* lA = lds[0];
  unsigned short* lB = lds[1];
  unsigned short* lflat = &lds[0][0];
  const int tid = threadIdx.x;
  const int lane = tid & 63, wave = tid >> 6;
  const int lr = lane & 15, lh = lane >> 4;
  const int chunk = gridDim.x >> 3;
  const int g2 = (blockIdx.x & 7) * chunk + (blockIdx.x >> 3);
  const int m0 = (g2 / NX) * 128, n0 = (g2 % NX) * 128;
  const int wm = (wave >> 1) * 64, wn = (wave & 1) * 64;
  floatx4 acc[4][4] = {};

  for (int k0 = 0; k0 < K; k0 += 64) {
    __syncthreads();
#pragma unroll
    for (int c0 = 0; c0 < 1024; c0 += 256) {
      int L = c0 + tid;
      int r = L >> 3;
      int c = (L & 7) ^ (r & 7);
      async_copy16(A + (size_t)(m0 + r) * K + k0 + c * 8, &lA[(size_t)(c0 + wave * 64) * 8]);
      async_copy16(B + (size_t)(n0 + r) * K + k0 + c * 8, &lB[(size_t)(c0 + wave * 64) * 8]);
    }
    __syncthreads();
#pragma unroll
    for (int kk = 0; kk < 2; ++kk) {
      short8 af[4], bfr[4];
#pragma unroll
      for (int mf = 0; mf < 4; ++mf)
        af[mf] = *(const short8*)&lA[(wm + mf * 16 + lr) * 64 + (((kk * 4 + lh) ^ (lr & 7)) * 8)];
#pragma unroll
      for (int nf = 0; nf < 4; ++nf)
        bfr[nf] = *(const short8*)&lB[(wn + nf * 16 + lr) * 64 + (((kk * 4 + lh) ^ (lr & 7)) * 8)];
#pragma unroll
      for (int mf = 0; mf < 4; ++mf)
#pragma unroll
        for (int nf = 0; nf < 4; ++nf)
          acc[mf][nf] = __builtin_amdgcn_mfma_f32_16x16x32_bf16(af[mf], bfr[nf], acc[mf][nf], 0, 0, 0);
    }
  }

  if (MODE == 1 && (n0 >> 10) == 2) {
    // V part: LDS-transposed coalesced store (R11, proven)
    __syncthreads();
#pragma unroll
    for (int mf = 0; mf < 4; ++mf) {
      int sl = (wm >> 2) + mf * 4 + lh;
#pragma unroll
      for (int nf = 0; nf < 4; ++nf) {
        int cl = wn + nf * 16 + lr;
        int hh = cl >> 6, dd = cl & 63;
        int sx = sl ^ ((dd & 3) << 3);
#pragma unroll
        for (int r = 0; r < 4; ++r) {
          float v = acc[mf][nf][r] + bias[n0 + cl];
          lflat[((r * 2 + hh) * 64 + dd) * 32 + sx] = f2bf(v);
        }
      }
    }
    __syncthreads();
    const int hbase = (n0 & 1023) >> 6;
    const int s0g = m0 >> 2;
    unsigned short* V = (unsigned short*)C + (size_t)2 * 64 * 2048 * 64;
#pragma unroll
    for (int k = 0; k < 8; ++k) {
      int f = tid + k * 256;
      int p = f >> 2, q = f & 3;
      int b = p >> 7, hh = (p >> 6) & 1, dd = p & 63;
      int g = b * 16 + hbase + hh;
      int sc = (q ^ (dd & 3)) * 8;
      short8 vv = *(const short8*)&lflat[p * 32 + q * 8];
      *(short8*)&V[((size_t)g * 64 + dd) * 2048 + s0g + sc] = vv;
    }
  } else {
#pragma unroll
    for (int mf = 0; mf < 4; ++mf)
#pragma unroll
      for (int nf = 0; nf < 4; ++nf)
#pragma unroll
        for (int r = 0; r < 4; ++r) {
          int row = m0 + wm + mf * 16 + lh * 4 + r;
          int col = n0 + wn + nf * 16 + lr;
          float v = acc[mf][nf][r] + bias[col];
          if (MODE == 0) {
            ((float*)C)[(size_t)row * N + col] = v;
          } else {
            int part = col >> 10, wi = col & 1023;
            int h = wi >> 6, dd = wi & 63;
            int s = row >> 2, b = row & 3;
            int gg = b * 16 + h;
            size_t base = (size_t)part * (64u * 2048u * 64u);
            if (part == 0) v *= 0.18033688011112042f;  // 1/sqrt(d_k)*log2(e)
            ((unsigned short*)C)[base + ((size_t)gg * 2048 + s) * 64 + dd] = f2bf(v);
          }
        }
  }
}

// ---------------------------------------------------------------- attention (32x32 MFMA)
// 1024 blocks (XCD-swizzled, causal-balanced qt). 4 waves x 32 q-rows, KV=64.
// Swapped QK^T on 32x32: S^T = mfma32(K,Q) -> lane owns q=lane&31.
//  - softmax: 31 in-lane + 1 shfl_xor(32); alpha/1l lane-local.
//  - P -> PV B-frag in-register: cvt_pk + shfl_xor(32) half-exchange (no lP LDS).
//  - O^T = mfma32(V,P): col q = lane&31 -> rescale lane-local.
// LDS 32KB (K,V dbuf only) -> 4-5 blocks/CU. Epilogue: O^T transposed via dead
// K/V LDS then fully-coalesced 16B stores.
__global__ __launch_bounds__(256) void attn_fwd(const unsigned short* __restrict__ Qb,
                                                const unsigned short* __restrict__ Kb,
                                                const unsigned short* __restrict__ Vt,
                                                unsigned short* __restrict__ Att,
                                                const int* __restrict__ causal_p) {
  __shared__ __align__(16) unsigned short smem[16384];  // [0,8192): K dbuf; [8192,16384): V dbuf
  const int tid = threadIdx.x;
  const int lane = tid & 63, w = tid >> 6;
  const int l31 = lane & 31, hi = lane >> 5;
  const int bid = blockIdx.x;
  const int g = (bid & 7) + 8 * (bid >> 7);
  int qt = (bid >> 3) & 15;
  qt = (qt & 12) | ((qt ^ (qt >> 2)) & 3);
  const int q0 = qt * 128;
  const int causal = causal_p[0];
  const size_t headOff = (size_t)g * 2048 * 64;
  const size_t vtHead = (size_t)g * 64 * 2048;
  const int q0w = q0 + w * 32;
  const int qg = q0w + l31;                 // this lane's q row

  // Q B-fragments (k = d): qf[c] covers d = c*16 + hi*8 .. +7
  short8 qf[4];
#pragma unroll
  for (int c = 0; c < 4; ++c)
    qf[c] = *(const short8*)&Qb[headOff + (size_t)qg * 64 + c * 16 + hi * 8];

  floatx16 oacc[2] = {};                    // O^T: lane col q=l31; rows d (2 d-tiles)
  float mrow = -1e30f, lrow = 0.f;

  const int nt = causal ? (q0 + 128) / 64 : 2048 / 64;
  const int qmax_w = q0w + 31;

  auto stageK = [&](int buf, int kv0) {
#pragma unroll
    for (int c0 = 0; c0 < 512; c0 += 256) {
      int L = c0 + tid;
      int kvr = L >> 3;
      int c = (tid & 7) ^ (kvr & 7);
      async_copy16(Kb + headOff + (size_t)(kv0 + kvr) * 64 + c * 8,
                   &smem[(size_t)buf * 4096 + (size_t)(c0 + w * 64) * 8]);
    }
  };
  auto stageV = [&](int buf, int kv0) {
#pragma unroll
    for (int c0 = 0; c0 < 512; c0 += 256) {
      int L = c0 + tid;
      int dr = L >> 3;
      int c = (tid & 7) ^ (dr & 7);
      async_copy16(Vt + vtHead + (size_t)dr * 2048 + kv0 + c * 8,
                   &smem[8192 + (size_t)buf * 4096 + (size_t)(c0 + w * 64) * 8]);
    }
  };

  stageK(0, 0);
  stageV(0, 0);
  int cur = 0;

  for (int t = 0; t < nt; ++t) {
    const int kv0 = t * 64;
    if (t + 1 < nt) {
      stageK(cur ^ 1, kv0 + 64);
      stageV(cur ^ 1, kv0 + 64);
      asm volatile("s_waitcnt vmcnt(4)" ::: "memory");
    } else {
      asm volatile("s_waitcnt vmcnt(0)" ::: "memory");
    }
    __builtin_amdgcn_s_barrier();
    asm volatile("" ::: "memory");

    if (!causal || kv0 <= qmax_w) {
      const unsigned short* lK = &smem[(size_t)cur * 4096];
      const unsigned short* lV = &smem[8192 + (size_t)cur * 4096];

      // ---- S^T = K * Q^T : sacc[st] lane: q=l31, kv = kv0+st*32+(r&3)+8*(r>>2)+4*hi
      floatx16 sacc[2] = {};
      __builtin_amdgcn_s_setprio(1);
#pragma unroll
      for (int st = 0; st < 2; ++st)
#pragma unroll
        for (int c = 0; c < 4; ++c) {
          int row = st * 32 + l31;
          short8 kf = *(const short8*)&lK[row * 64 + (((2 * c + hi) ^ (row & 7)) * 8)];
          sacc[st] = __builtin_amdgcn_mfma_f32_32x32x16_bf16(kf, qf[c], sacc[st], 0, 0, 0);
        }
      __builtin_amdgcn_s_setprio(0);

      if (causal && kv0 + 63 > q0w) {
#pragma unroll
        for (int st = 0; st < 2; ++st)
#pragma unroll
          for (int r = 0; r < 16; ++r) {
            int kv = kv0 + st * 32 + (r & 3) + 8 * (r >> 2) + 4 * hi;
            if (kv > qg) sacc[st][r] = -1e30f;
          }
      }

      // ---- online softmax (lane-local q)
      float rm = -1e30f;
#pragma unroll
      for (int st = 0; st < 2; ++st)
#pragma unroll
        for (int r = 0; r < 16; ++r)
          rm = fmaxf(rm, sacc[st][r]);
      rm = fmaxf(rm, __shfl_xor(rm, 32, 64));
      float mn = fmaxf(mrow, rm);
      float alpha = fexp2(mrow - mn);
      mrow = mn;
      float rs = 0.f;
#pragma unroll
      for (int st = 0; st < 2; ++st)
#pragma unroll
        for (int r = 0; r < 16; ++r) {
          float p = fexp2(sacc[st][r] - mn);
          sacc[st][r] = p;
          rs += p;
        }
      rs += __shfl_xor(rs, 32, 64);
      lrow = lrow * alpha + rs;
#pragma unroll
      for (int dt = 0; dt < 2; ++dt)
#pragma unroll
        for (int r = 0; r < 16; ++r)
          oacc[dt][r] *= alpha;

      // ---- P B-frags in-register + PV: O^T += V * P
#pragma unroll
      for (int st = 0; st < 2; ++st)
#pragma unroll
        for (int h = 0; h < 2; ++h) {
          unsigned int C1 = cvt_pk_bf16(sacc[st][8 * h + 0], sacc[st][8 * h + 1]);
          unsigned int C2 = cvt_pk_bf16(sacc[st][8 * h + 2], sacc[st][8 * h + 3]);
          unsigned int C3 = cvt_pk_bf16(sacc[st][8 * h + 4], sacc[st][8 * h + 5]);
          unsigned int C4 = cvt_pk_bf16(sacc[st][8 * h + 6], sacc[st][8 * h + 7]);
          unsigned int P1 = hi ? C1 : C3, P2 = hi ? C2 : C4;
          unsigned int R1 = (unsigned int)__shfl_xor((int)P1, 32, 64);
          unsigned int R2 = (unsigned int)__shfl_xor((int)P2, 32, 64);
          union { unsigned int u[4]; short8 s; } pf;
          pf.u[0] = hi ? R1 : C1; pf.u[1] = hi ? R2 : C2;
          pf.u[2] = hi ? C3 : R1; pf.u[3] = hi ? C4 : R2;
          __builtin_amdgcn_s_setprio(1);
#pragma unroll
          for (int dt = 0; dt < 2; ++dt) {
            int row = dt * 32 + l31;
            short8 vf = *(const short8*)&lV[row * 64 + (((st * 4 + h * 2 + hi) ^ (row & 7)) * 8)];
            oacc[dt] = __builtin_amdgcn_mfma_f32_32x32x16_bf16(vf, pf.s, oacc[dt], 0, 0, 0);
          }
          __builtin_amdgcn_s_setprio(0);
        }
    }
    asm volatile("" ::: "memory");
    __builtin_amdgcn_s_barrier();
    cur ^= 1;
  }

  // ---- epilogue: normalize (lane-local), transpose via LDS, coalesced store
  float inv = 1.f / lrow;
#pragma unroll
  for (int dt = 0; dt < 2; ++dt)
#pragma unroll
    for (int r = 0; r < 16; ++r)
      oacc[dt][r] *= inv;

  unsigned short* ov = smem;                 // 128 rows x 68 shorts (17KB < 32KB)
  const int ql = w * 32 + l31;
#pragma unroll
  for (int dt = 0; dt < 2; ++dt)
#pragma unroll
    for (int tt = 0; tt < 4; ++tt) {
      int d0 = dt * 32 + 8 * tt + 4 * hi;
      uint2 pk;
      pk.x = cvt_pk_bf16(oacc[dt][4 * tt + 0], oacc[dt][4 * tt + 1]);
      pk.y = cvt_pk_bf16(oacc[dt][4 * tt + 2], oacc[dt][4 * tt + 3]);
      *(uint2*)&ov[ql * 68 + d0] = pk;
    }
  __syncthreads();
  const int bb = g >> 4, hh = g & 15;
#pragma unroll
  for (int k = 0; k < 4; ++k) {
    int row = (tid >> 3) + k * 32;
    short8 vv = *(const short8*)&ov[row * 68 + (tid & 7) * 8];
    int sg = q0 + row;
    *(short8*)&Att[((size_t)sg * 4 + bb) * 1024 + hh * 64 + (tid & 7) * 8] = vv;
  }
}

// ---------------------------------------------------------------- launcher
extern "C" void kernel_launch(void* const* d_in, const int* in_sizes, int n_in,
                              void* d_out, int out_size, void* d_ws, size_t ws_size,
                              hipStream_t stream) {
  const float* x     = (const float*)d_in[0];
  const float* w_qkv = (const float*)d_in[1];
  const float* b_qkv = (const float*)d_in[2];
  const float* w_out = (const float*)d_in[3];
  const float* b_out = (const float*)d_in[4];
  const int*   causal = (const int*)d_in[5];
  float* out = (float*)d_out;

  char* ws = (char*)d_ws;
  size_t off = 0;
  auto alloc = [&](size_t bytes) { char* p = ws + off; off += (bytes + 255) & ~(size_t)255; return p; };
  unsigned short* Xbf  = (unsigned short*)alloc((size_t)8192 * 1024 * 2);
  unsigned short* Wqkv = (unsigned short*)alloc((size_t)3072 * 1024 * 2);
  unsigned short* Wout = (unsigned short*)alloc((size_t)1024 * 1024 * 2);
  unsigned short* QKV  = (unsigned short*)alloc((size_t)3 * 64 * 2048 * 64 * 2);
  unsigned short* Att  = (unsigned short*)alloc((size_t)8192 * 1024 * 2);
  (void)ws_size; (void)in_sizes; (void)n_in; (void)out_size;

  cvt_all<<<12288, 256, 0, stream>>>(x, w_qkv, w_out, Xbf, Wqkv, Wout);

  gemm_nt<1, 24><<<24 * 64, 256, 0, stream>>>(Xbf, Wqkv, b_qkv, (void*)QKV, 8192, 3072, 1024);

  const unsigned short* Qh = QKV;
  const unsigned short* Kh = QKV + (size_t)64 * 2048 * 64;
  const unsigned short* Vh = QKV + (size_t)2 * 64 * 2048 * 64;
  attn_fwd<<<1024, 256, 0, stream>>>(Qh, Kh, Vh, Att, causal);

  gemm_nt<0, 8><<<8 * 64, 256, 0, stream>>>(Att, Wout, b_out, (void*)out, 8192, 1024, 1024);
}

// Round 13
// 154.315 us; speedup vs baseline: 1.1449x; 1.1449x over previous
//
#include <hip/hip_runtime.h>

typedef __attribute__((ext_vector_type(8))) short short8;
typedef __attribute__((ext_vector_type(4))) float floatx4;
typedef __attribute__((ext_vector_type(16))) float floatx16;
typedef __attribute__((ext_vector_type(4))) unsigned short ushort4v;

__device__ __forceinline__ unsigned short f2bf(float f) {
  unsigned int u = __float_as_uint(f);
  u += 0x7FFFu + ((u >> 16) & 1u);           // round-to-nearest-even
  return (unsigned short)(u >> 16);
}

__device__ __forceinline__ unsigned int cvt_pk_bf16(float lo, float hi) {
  unsigned int r;
  asm("v_cvt_pk_bf16_f32 %0, %1, %2" : "=v"(r) : "v"(lo), "v"(hi));
  return r;
}

__device__ __forceinline__ void async_copy16(const void* g, void* l) {
  __builtin_amdgcn_global_load_lds(
      (const __attribute__((address_space(1))) unsigned int*)g,
      (__attribute__((address_space(3))) unsigned int*)l, 16, 0, 0);
}

__device__ __forceinline__ float fexp2(float x) {
#if __has_builtin(__builtin_amdgcn_exp2f)
  return __builtin_amdgcn_exp2f(x);
#else
  return exp2f(x);
#endif
}

// ---------------------------------------------------------------- convert (fused)
__global__ __launch_bounds__(256) void cvt_all(const float* __restrict__ x,
                                               const float* __restrict__ wq,
                                               const float* __restrict__ wo,
                                               unsigned short* __restrict__ Xb,
                                               unsigned short* __restrict__ Wqb,
                                               unsigned short* __restrict__ Wob) {
  int i = blockIdx.x * blockDim.x + threadIdx.x;
  const float* src;
  unsigned short* dst;
  int off;
  if (i < 2097152) { src = x;  dst = Xb;  off = i; }
  else if (i < 2883584) { src = wq; dst = Wqb; off = i - 2097152; }
  else { src = wo; dst = Wob; off = i - 2883584; }
  float4 v = reinterpret_cast<const float4*>(src)[off];
  ushort4v o;
  o[0] = f2bf(v.x); o[1] = f2bf(v.y); o[2] = f2bf(v.z); o[3] = f2bf(v.w);
  reinterpret_cast<ushort4v*>(dst)[off] = o;
}

// ---------------------------------------------------------------- GEMM NT 128x128 (R11)
template <int MODE, int NX>
__global__ __launch_bounds__(256, 4) void gemm_nt(const unsigned short* __restrict__ A,
                                                  const unsigned short* __restrict__ B,
                                                  const float* __restrict__ bias,
                                                  void* __restrict__ C,
                                                  int M, int N, int K) {
  __shared__ __align__(16) unsigned short lds[2][128 * 64];
  unsigned short* lA = lds[0];
  unsigned short* lB = lds[1];
  unsigned short* lflat = &lds[0][0];
  const int tid = threadIdx.x;
  const int lane = tid & 63, wave = tid >> 6;
  const int lr = lane & 15, lh = lane >> 4;
  const int chunk = gridDim.x >> 3;
  const int g2 = (blockIdx.x & 7) * chunk + (blockIdx.x >> 3);
  const int m0 = (g2 / NX) * 128, n0 = (g2 % NX) * 128;
  const int wm = (wave >> 1) * 64, wn = (wave & 1) * 64;
  floatx4 acc[4][4] = {};

  for (int k0 = 0; k0 < K; k0 += 64) {
    __syncthreads();
#pragma unroll
    for (int c0 = 0; c0 < 1024; c0 += 256) {
      int L = c0 + tid;
      int r = L >> 3;
      int c = (L & 7) ^ (r & 7);
      async_copy16(A + (size_t)(m0 + r) * K + k0 + c * 8, &lA[(size_t)(c0 + wave * 64) * 8]);
      async_copy16(B + (size_t)(n0 + r) * K + k0 + c * 8, &lB[(size_t)(c0 + wave * 64) * 8]);
    }
    __syncthreads();
#pragma unroll
    for (int kk = 0; kk < 2; ++kk) {
      short8 af[4], bfr[4];
#pragma unroll
      for (int mf = 0; mf < 4; ++mf)
        af[mf] = *(const short8*)&lA[(wm + mf * 16 + lr) * 64 + (((kk * 4 + lh) ^ (lr & 7)) * 8)];
#pragma unroll
      for (int nf = 0; nf < 4; ++nf)
        bfr[nf] = *(const short8*)&lB[(wn + nf * 16 + lr) * 64 + (((kk * 4 + lh) ^ (lr & 7)) * 8)];
#pragma unroll
      for (int mf = 0; mf < 4; ++mf)
#pragma unroll
        for (int nf = 0; nf < 4; ++nf)
          acc[mf][nf] = __builtin_amdgcn_mfma_f32_16x16x32_bf16(af[mf], bfr[nf], acc[mf][nf], 0, 0, 0);
    }
  }

  if (MODE == 1 && (n0 >> 10) == 2) {
    // V part: LDS-transposed coalesced store (R11, proven)
    __syncthreads();
#pragma unroll
    for (int mf = 0; mf < 4; ++mf) {
      int sl = (wm >> 2) + mf * 4 + lh;
#pragma unroll
      for (int nf = 0; nf < 4; ++nf) {
        int cl = wn + nf * 16 + lr;
        int hh = cl >> 6, dd = cl & 63;
        int sx = sl ^ ((dd & 3) << 3);
#pragma unroll
        for (int r = 0; r < 4; ++r) {
          float v = acc[mf][nf][r] + bias[n0 + cl];
          lflat[((r * 2 + hh) * 64 + dd) * 32 + sx] = f2bf(v);
        }
      }
    }
    __syncthreads();
    const int hbase = (n0 & 1023) >> 6;
    const int s0g = m0 >> 2;
    unsigned short* V = (unsigned short*)C + (size_t)2 * 64 * 2048 * 64;
#pragma unroll
    for (int k = 0; k < 8; ++k) {
      int f = tid + k * 256;
      int p = f >> 2, q = f & 3;
      int b = p >> 7, hh = (p >> 6) & 1, dd = p & 63;
      int g = b * 16 + hbase + hh;
      int sc = (q ^ (dd & 3)) * 8;
      short8 vv = *(const short8*)&lflat[p * 32 + q * 8];
      *(short8*)&V[((size_t)g * 64 + dd) * 2048 + s0g + sc] = vv;
    }
  } else {
#pragma unroll
    for (int mf = 0; mf < 4; ++mf)
#pragma unroll
      for (int nf = 0; nf < 4; ++nf)
#pragma unroll
        for (int r = 0; r < 4; ++r) {
          int row = m0 + wm + mf * 16 + lh * 4 + r;
          int col = n0 + wn + nf * 16 + lr;
          float v = acc[mf][nf][r] + bias[col];
          if (MODE == 0) {
            ((float*)C)[(size_t)row * N + col] = v;
          } else {
            int part = col >> 10, wi = col & 1023;
            int h = wi >> 6, dd = wi & 63;
            int s = row >> 2, b = row & 3;
            int gg = b * 16 + h;
            size_t base = (size_t)part * (64u * 2048u * 64u);
            if (part == 0) v *= 0.18033688011112042f;  // 1/sqrt(d_k)*log2(e)
            ((unsigned short*)C)[base + ((size_t)gg * 2048 + s) * 64 + dd] = f2bf(v);
          }
        }
  }
}

// ---------------------------------------------------------------- attention (32x32 MFMA)
// R13: dispatch-balance fix. A CU's 4 co-resident blocks differ in bid bits
// b8-b9 (round-robin CU assignment); route those into qt so every CU gets
// qt in {15-j, j, 11-j, 4+j} -- per-CU tile sum 68 for all j, longest-first
// (LPT). Head g from {b0-2, b7, b5-6}: same-head blocks keep bid&7 -> same
// XCD (K/V L2 locality). Plus defer-rescale THR=8 (T13).
__global__ __launch_bounds__(256) void attn_fwd(const unsigned short* __restrict__ Qb,
                                                const unsigned short* __restrict__ Kb,
                                                const unsigned short* __restrict__ Vt,
                                                unsigned short* __restrict__ Att,
                                                const int* __restrict__ causal_p) {
  __shared__ __align__(16) unsigned short smem[16384];  // [0,8192): K dbuf; [8192,16384): V dbuf
  const int tid = threadIdx.x;
  const int lane = tid & 63, w = tid >> 6;
  const int l31 = lane & 31, hi = lane >> 5;
  const int bid = blockIdx.x;
  const int jj = (bid >> 3) & 3;
  const int mm = (bid >> 5) & 3;
  const int kk2 = (bid >> 8) & 3;
  const int g = (bid & 7) + 8 * ((bid >> 7) & 1) + 16 * mm;
  const int qt = (kk2 == 0) ? (15 - jj) : (kk2 == 1) ? jj : (kk2 == 2) ? (11 - jj) : (4 + jj);
  const int q0 = qt * 128;
  const int causal = causal_p[0];
  const size_t headOff = (size_t)g * 2048 * 64;
  const size_t vtHead = (size_t)g * 64 * 2048;
  const int q0w = q0 + w * 32;
  const int qg = q0w + l31;                 // this lane's q row

  short8 qf[4];
#pragma unroll
  for (int c = 0; c < 4; ++c)
    qf[c] = *(const short8*)&Qb[headOff + (size_t)qg * 64 + c * 16 + hi * 8];

  floatx16 oacc[2] = {};                    // O^T: lane col q=l31; rows d
  float mrow = -1e30f, lrow = 0.f;

  const int nt = causal ? (q0 + 128) / 64 : 2048 / 64;
  const int qmax_w = q0w + 31;

  auto stageK = [&](int buf, int kv0) {
#pragma unroll
    for (int c0 = 0; c0 < 512; c0 += 256) {
      int L = c0 + tid;
      int kvr = L >> 3;
      int c = (tid & 7) ^ (kvr & 7);
      async_copy16(Kb + headOff + (size_t)(kv0 + kvr) * 64 + c * 8,
                   &smem[(size_t)buf * 4096 + (size_t)(c0 + w * 64) * 8]);
    }
  };
  auto stageV = [&](int buf, int kv0) {
#pragma unroll
    for (int c0 = 0; c0 < 512; c0 += 256) {
      int L = c0 + tid;
      int dr = L >> 3;
      int c = (tid & 7) ^ (dr & 7);
      async_copy16(Vt + vtHead + (size_t)dr * 2048 + kv0 + c * 8,
                   &smem[8192 + (size_t)buf * 4096 + (size_t)(c0 + w * 64) * 8]);
    }
  };

  stageK(0, 0);
  stageV(0, 0);
  int cur = 0;

  for (int t = 0; t < nt; ++t) {
    const int kv0 = t * 64;
    if (t + 1 < nt) {
      stageK(cur ^ 1, kv0 + 64);
      stageV(cur ^ 1, kv0 + 64);
      asm volatile("s_waitcnt vmcnt(4)" ::: "memory");
    } else {
      asm volatile("s_waitcnt vmcnt(0)" ::: "memory");
    }
    __builtin_amdgcn_s_barrier();
    asm volatile("" ::: "memory");

    if (!causal || kv0 <= qmax_w) {
      const unsigned short* lK = &smem[(size_t)cur * 4096];
      const unsigned short* lV = &smem[8192 + (size_t)cur * 4096];

      floatx16 sacc[2] = {};
      __builtin_amdgcn_s_setprio(1);
#pragma unroll
      for (int st = 0; st < 2; ++st)
#pragma unroll
        for (int c = 0; c < 4; ++c) {
          int row = st * 32 + l31;
          short8 kf = *(const short8*)&lK[row * 64 + (((2 * c + hi) ^ (row & 7)) * 8)];
          sacc[st] = __builtin_amdgcn_mfma_f32_32x32x16_bf16(kf, qf[c], sacc[st], 0, 0, 0);
        }
      __builtin_amdgcn_s_setprio(0);

      if (causal && kv0 + 63 > q0w) {
#pragma unroll
        for (int st = 0; st < 2; ++st)
#pragma unroll
          for (int r = 0; r < 16; ++r) {
            int kv = kv0 + st * 32 + (r & 3) + 8 * (r >> 2) + 4 * hi;
            if (kv > qg) sacc[st][r] = -1e30f;
          }
      }

      // online softmax (lane-local q), defer-rescale THR=8 (T13)
      float rm = -1e30f;
#pragma unroll
      for (int st = 0; st < 2; ++st)
#pragma unroll
        for (int r = 0; r < 16; ++r)
          rm = fmaxf(rm, sacc[st][r]);
      rm = fmaxf(rm, __shfl_xor(rm, 32, 64));
      if (!__all(rm - mrow <= 8.f)) {
        float mn = fmaxf(mrow, rm);
        float alpha = fexp2(mrow - mn);
        mrow = mn;
        lrow *= alpha;
#pragma unroll
        for (int dt = 0; dt < 2; ++dt)
#pragma unroll
          for (int r = 0; r < 16; ++r)
            oacc[dt][r] *= alpha;
      }
      float rs = 0.f;
#pragma unroll
      for (int st = 0; st < 2; ++st)
#pragma unroll
        for (int r = 0; r < 16; ++r) {
          float p = fexp2(sacc[st][r] - mrow);
          sacc[st][r] = p;
          rs += p;
        }
      rs += __shfl_xor(rs, 32, 64);
      lrow += rs;

      // P B-frags in-register + PV: O^T += V * P
#pragma unroll
      for (int st = 0; st < 2; ++st)
#pragma unroll
        for (int h = 0; h < 2; ++h) {
          unsigned int C1 = cvt_pk_bf16(sacc[st][8 * h + 0], sacc[st][8 * h + 1]);
          unsigned int C2 = cvt_pk_bf16(sacc[st][8 * h + 2], sacc[st][8 * h + 3]);
          unsigned int C3 = cvt_pk_bf16(sacc[st][8 * h + 4], sacc[st][8 * h + 5]);
          unsigned int C4 = cvt_pk_bf16(sacc[st][8 * h + 6], sacc[st][8 * h + 7]);
          unsigned int P1 = hi ? C1 : C3, P2 = hi ? C2 : C4;
          unsigned int R1 = (unsigned int)__shfl_xor((int)P1, 32, 64);
          unsigned int R2 = (unsigned int)__shfl_xor((int)P2, 32, 64);
          union { unsigned int u[4]; short8 s; } pf;
          pf.u[0] = hi ? R1 : C1; pf.u[1] = hi ? R2 : C2;
          pf.u[2] = hi ? C3 : R1; pf.u[3] = hi ? C4 : R2;
          __builtin_amdgcn_s_setprio(1);
#pragma unroll
          for (int dt = 0; dt < 2; ++dt) {
            int row = dt * 32 + l31;
            short8 vf = *(const short8*)&lV[row * 64 + (((st * 4 + h * 2 + hi) ^ (row & 7)) * 8)];
            oacc[dt] = __builtin_amdgcn_mfma_f32_32x32x16_bf16(vf, pf.s, oacc[dt], 0, 0, 0);
          }
          __builtin_amdgcn_s_setprio(0);
        }
    }
    asm volatile("" ::: "memory");
    __builtin_amdgcn_s_barrier();
    cur ^= 1;
  }

  float inv = 1.f / lrow;
#pragma unroll
  for (int dt = 0; dt < 2; ++dt)
#pragma unroll
    for (int r = 0; r < 16; ++r)
      oacc[dt][r] *= inv;

  unsigned short* ov = smem;                 // 128 rows x 68 shorts
  const int ql = w * 32 + l31;
#pragma unroll
  for (int dt = 0; dt < 2; ++dt)
#pragma unroll
    for (int tt = 0; tt < 4; ++tt) {
      int d0 = dt * 32 + 8 * tt + 4 * hi;
      uint2 pk;
      pk.x = cvt_pk_bf16(oacc[dt][4 * tt + 0], oacc[dt][4 * tt + 1]);
      pk.y = cvt_pk_bf16(oacc[dt][4 * tt + 2], oacc[dt][4 * tt + 3]);
      *(uint2*)&ov[ql * 68 + d0] = pk;
    }
  __syncthreads();
  const int bb = g >> 4, hh = g & 15;
#pragma unroll
  for (int k = 0; k < 4; ++k) {
    int row = (tid >> 3) + k * 32;
    short8 vv = *(const short8*)&ov[row * 68 + (tid & 7) * 8];
    int sg = q0 + row;
    *(short8*)&Att[((size_t)sg * 4 + bb) * 1024 + hh * 64 + (tid & 7) * 8] = vv;
  }
}

// ---------------------------------------------------------------- launcher
extern "C" void kernel_launch(void* const* d_in, const int* in_sizes, int n_in,
                              void* d_out, int out_size, void* d_ws, size_t ws_size,
                              hipStream_t stream) {
  const float* x     = (const float*)d_in[0];
  const float* w_qkv = (const float*)d_in[1];
  const float* b_qkv = (const float*)d_in[2];
  const float* w_out = (const float*)d_in[3];
  const float* b_out = (const float*)d_in[4];
  const int*   causal = (const int*)d_in[5];
  float* out = (float*)d_out;

  char* ws = (char*)d_ws;
  size_t off = 0;
  auto alloc = [&](size_t bytes) { char* p = ws + off; off += (bytes + 255) & ~(size_t)255; return p; };
  unsigned short* Xbf  = (unsigned short*)alloc((size_t)8192 * 1024 * 2);
  unsigned short* Wqkv = (unsigned short*)alloc((size_t)3072 * 1024 * 2);
  unsigned short* Wout = (unsigned short*)alloc((size_t)1024 * 1024 * 2);
  unsigned short* QKV  = (unsigned short*)alloc((size_t)3 * 64 * 2048 * 64 * 2);
  unsigned short* Att  = (unsigned short*)alloc((size_t)8192 * 1024 * 2);
  (void)ws_size; (void)in_sizes; (void)n_in; (void)out_size;

  cvt_all<<<12288, 256, 0, stream>>>(x, w_qkv, w_out, Xbf, Wqkv, Wout);

  gemm_nt<1, 24><<<24 * 64, 256, 0, stream>>>(Xbf, Wqkv, b_qkv, (void*)QKV, 8192, 3072, 1024);

  const unsigned short* Qh = QKV;
  const unsigned short* Kh = QKV + (size_t)64 * 2048 * 64;
  const unsigned short* Vh = QKV + (size_t)2 * 64 * 2048 * 64;
  attn_fwd<<<1024, 256, 0, stream>>>(Qh, Kh, Vh, Att, causal);

  gemm_nt<0, 8><<<8 * 64, 256, 0, stream>>>(Att, Wout, b_out, (void*)out, 8192, 1024, 1024);
}